// Round 13
// baseline (278.898 us; speedup 1.0000x reference)
//
#include <hip/hip_runtime.h>

// GCN 2-layer + BatchNorm1d forward.
// R13: launch-count reduction 13 -> 10 (R12 accounting: ~50us of inter-dispatch
//      gaps). (1) wprep folded into hist_k (block 0); (2) prescale folded into
//      buildC (dis kept in LDS, bucket's 128 emb rows -> es in-kernel);
//      (3) bn_part folded into layer-2 agg64 (per-block partials from the
//      epilogue registers, plain stores, no atomics); (4) bn_final widened to
//      1024 threads for the 6250-partial reduce.
// Kept: counting-sort CSR, R8-form agg64 gathers (FETCH = 86MB unique-line
//      floor, ~3.4TB/s fill ceiling -> ~27us each is the floor), MFMA GEMM
//      (verified 16x16x32_f16 layouts), fp16 tables, atomic-free BN.
// Pipeline: hist(+wprep) -> scan_bucket -> scan_total -> scatB ->
//   buildC(CSR+dis+es) -> agg64 ag1 -> gemmAB_mfma hs2 -> agg64 h2(+BN part)
//   -> bn_final -> bn_apply -> d_out f32.

#define EPS_BN 1e-5f
#define NBKT_PAD 1024   // >= ceil(N/128); N=100000 -> 782 buckets
#define SCAT_B 256      // edge-pass blocks (1024 threads each)

typedef _Float16 f16;
typedef _Float16 f16x2 __attribute__((ext_vector_type(2)));
typedef _Float16 f16x8 __attribute__((ext_vector_type(8)));
typedef float f32x4 __attribute__((ext_vector_type(4)));
union pk4 { ushort4 u; f16 h[4]; f16x2 h2[2]; };

// ---------------- hist (+wprep in block 0) ----------------
__global__ __launch_bounds__(1024) void hist_k(const int* __restrict__ colv, int E, int epb,
                                               int* __restrict__ ghist,
                                               const float* __restrict__ W1, const float* __restrict__ W2,
                                               f16* __restrict__ w1t, f16* __restrict__ w2t) {
    __shared__ int bins[NBKT_PAD];
    int tid = threadIdx.x;
    bins[tid] = 0;
    __syncthreads();
    int e0 = blockIdx.x * epb;
    int e1 = min(E, e0 + epb);
    for (int e = e0 + tid; e < e1; e += 1024)
        atomicAdd(&bins[colv[e] >> 7], 1);
    __syncthreads();
    ghist[blockIdx.x * NBKT_PAD + tid] = bins[tid];
    if (blockIdx.x == 0) {                        // fused wprep
        for (int t = tid; t < 16384; t += 1024) {
            if (t < 8192) {                       // W1 [64][128] -> w1t [128][64]
                int k = t >> 7, c = t & 127;
                w1t[c * 64 + k] = (f16)W1[t];
            } else {                              // W2 [128][64] -> w2t [64][128]
                int i = t - 8192;
                int k = i >> 6, c = i & 63;
                w2t[c * 128 + k] = (f16)W2[i];
            }
        }
    }
}

// ---------------- scan_bucket: per-bucket exclusive prefix over the 256 blocks ----------------
__global__ __launch_bounds__(256) void scan_bucket_k(int* __restrict__ ghist, int* __restrict__ bcnt) {
    __shared__ int s[256];
    int k = blockIdx.x;
    int b = threadIdx.x;
    int v = ghist[b * NBKT_PAD + k];
    s[b] = v; __syncthreads();
    for (int off = 1; off < 256; off <<= 1) {
        int t = (b >= off) ? s[b - off] : 0;
        __syncthreads();
        s[b] += t;
        __syncthreads();
    }
    ghist[b * NBKT_PAD + k] = s[b] - v;           // exclusive within bucket
    if (b == 255) bcnt[k] = s[255];
}

// ---------------- scan_total: exclusive scan of bucket totals ----------------
__global__ __launch_bounds__(1024) void scan_total_k(const int* __restrict__ bcnt,
                                                     int* __restrict__ bstart,
                                                     int* __restrict__ start, int n, int E) {
    __shared__ int s[1024];
    int tid = threadIdx.x;
    int v = bcnt[tid];
    s[tid] = v; __syncthreads();
    for (int off = 1; off < 1024; off <<= 1) {
        int t = (tid >= off) ? s[tid - off] : 0;
        __syncthreads();
        s[tid] += t;
        __syncthreads();
    }
    bstart[tid] = s[tid] - v;
    if (tid == 1023) bstart[1024] = s[1023];
    if (tid == 0) start[n] = E;
}

// ---------------- scatB: single-pass scatter (cursor = ghist + bstart) ----------------
__global__ __launch_bounds__(1024) void scatB_k(const int* __restrict__ rowv, const int* __restrict__ colv,
                                                int E, int epb, const int* __restrict__ ghist,
                                                const int* __restrict__ bstart,
                                                unsigned* __restrict__ ebuf) {
    __shared__ int bins[NBKT_PAD];
    int tid = threadIdx.x;
    bins[tid] = ghist[blockIdx.x * NBKT_PAD + tid] + bstart[tid];
    __syncthreads();
    int e0 = blockIdx.x * epb;
    int e1 = min(E, e0 + epb);
    for (int e = e0 + tid; e < e1; e += 1024) {
        int c = colv[e];
        int p = atomicAdd(&bins[c >> 7], 1);
        ebuf[p] = ((unsigned)rowv[e] << 7) | (unsigned)(c & 127);
    }
}

// ---------------- buildC: per-bucket CSR finalize + fused prescale (es) ----------------
__global__ __launch_bounds__(512) void buildC_k(const unsigned* __restrict__ ebuf,
                                                const int* __restrict__ bstart,
                                                int* __restrict__ start, int* __restrict__ srcs,
                                                float* __restrict__ dis,
                                                const float* __restrict__ emb, f16* __restrict__ es, int n) {
    __shared__ int ncnt[128], noff[128], stmp[128];
    __shared__ float sdis[128];
    int b = blockIdx.x;
    int tid = threadIdx.x;
    int e0 = bstart[b], e1 = bstart[b + 1];
    if (tid < 128) ncnt[tid] = 0;
    __syncthreads();
    for (int e = e0 + tid; e < e1; e += 512)
        atomicAdd(&ncnt[ebuf[e] & 127u], 1);
    __syncthreads();
    if (tid < 128) stmp[tid] = ncnt[tid];
    __syncthreads();
    for (int off = 1; off < 128; off <<= 1) {
        int t = (tid < 128 && tid >= off) ? stmp[tid - off] : 0;
        __syncthreads();
        if (tid < 128) stmp[tid] += t;
        __syncthreads();
    }
    if (tid < 128) {
        int excl = stmp[tid] - ncnt[tid];
        noff[tid] = e0 + excl;
        float d = rsqrtf((float)(ncnt[tid] + 1));         // +1 self-loop
        sdis[tid] = d;
        int node = b * 128 + tid;
        if (node < n) {
            start[node] = e0 + excl;
            dis[node] = d;
        }
    }
    __syncthreads();
    for (int e = e0 + tid; e < e1; e += 512) {
        unsigned p = ebuf[e];
        int pos = atomicAdd(&noff[p & 127u], 1);
        srcs[pos] = (int)(p >> 7);
    }
    // fused prescale: es[node] = fp16(dis * emb[node]) for this bucket's nodes
    for (int i = tid; i < 2048; i += 512) {               // 128 rows x 16 quads
        int r = i >> 4, q = i & 15;
        int node = b * 128 + r;
        if (node < n) {
            float d = sdis[r];
            float4 v = ((const float4*)emb)[(size_t)node * 16 + q];
            pk4 p;
            p.h[0] = (f16)(v.x * d); p.h[1] = (f16)(v.y * d);
            p.h[2] = (f16)(v.z * d); p.h[3] = (f16)(v.w * d);
            ((ushort4*)es)[(size_t)node * 16 + q] = p.u;
        }
    }
}

__device__ __forceinline__ void acc_pk(float4& acc, ushort4 u) {
    pk4 p; p.u = u;
    acc.x += (float)p.h[0]; acc.y += (float)p.h[1];
    acc.z += (float)p.h[2]; acc.w += (float)p.h[3];
}

// ---------------- agg64: 16 lanes/node, 8-deep unroll, pure gather ----------------
// If pbuf != null, also emits per-block BN partials (sum, sumsq per column).
__global__ __launch_bounds__(256) void agg64_k(const f16* __restrict__ table, const int* __restrict__ start,
                                               const int* __restrict__ srcs, const float* __restrict__ dis,
                                               const float* __restrict__ bias, f16* __restrict__ out,
                                               float* __restrict__ pbuf, int n) {
    __shared__ float4 ls[256], lq[256];
    int node = blockIdx.x * 16 + (threadIdx.x >> 4);
    bool active = node < n;
    int lane = threadIdx.x & 15;
    const ushort4* t4 = (const ushort4*)table;
    float4 acc = make_float4(0.f, 0.f, 0.f, 0.f);
    int s0 = 0, s1 = 0;
    if (active) {
        acc_pk(acc, t4[(size_t)node * 16 + lane]);        // self-loop term
        s0 = start[node]; s1 = start[node + 1];
    }
    int e = s0;
    for (; e + 7 < s1; e += 8) {
        int i0 = srcs[e],     i1 = srcs[e + 1], i2 = srcs[e + 2], i3 = srcs[e + 3];
        int i4 = srcs[e + 4], i5 = srcs[e + 5], i6 = srcs[e + 6], i7 = srcs[e + 7];
        ushort4 v0 = t4[(size_t)i0 * 16 + lane];
        ushort4 v1 = t4[(size_t)i1 * 16 + lane];
        ushort4 v2 = t4[(size_t)i2 * 16 + lane];
        ushort4 v3 = t4[(size_t)i3 * 16 + lane];
        ushort4 v4 = t4[(size_t)i4 * 16 + lane];
        ushort4 v5 = t4[(size_t)i5 * 16 + lane];
        ushort4 v6 = t4[(size_t)i6 * 16 + lane];
        ushort4 v7 = t4[(size_t)i7 * 16 + lane];
        acc_pk(acc, v0); acc_pk(acc, v1); acc_pk(acc, v2); acc_pk(acc, v3);
        acc_pk(acc, v4); acc_pk(acc, v5); acc_pk(acc, v6); acc_pk(acc, v7);
    }
    for (; e + 3 < s1; e += 4) {
        int i0 = srcs[e], i1 = srcs[e + 1], i2 = srcs[e + 2], i3 = srcs[e + 3];
        ushort4 v0 = t4[(size_t)i0 * 16 + lane];
        ushort4 v1 = t4[(size_t)i1 * 16 + lane];
        ushort4 v2 = t4[(size_t)i2 * 16 + lane];
        ushort4 v3 = t4[(size_t)i3 * 16 + lane];
        acc_pk(acc, v0); acc_pk(acc, v1); acc_pk(acc, v2); acc_pk(acc, v3);
    }
    for (; e < s1; e++) acc_pk(acc, t4[(size_t)srcs[e] * 16 + lane]);
    float4 o = make_float4(0.f, 0.f, 0.f, 0.f);
    if (active) {
        float d = dis[node];
        float4 b = make_float4(0.f, 0.f, 0.f, 0.f);
        if (bias) b = ((const float4*)bias)[lane];
        o.x = acc.x * d + b.x; o.y = acc.y * d + b.y;
        o.z = acc.z * d + b.z; o.w = acc.w * d + b.w;
        pk4 p;
        p.h[0] = (f16)o.x; p.h[1] = (f16)o.y; p.h[2] = (f16)o.z; p.h[3] = (f16)o.w;
        ((ushort4*)out)[(size_t)node * 16 + lane] = p.u;
    }
    if (pbuf) {                                   // fused BN partials (uniform branch)
        float4 sq;
        sq.x = o.x * o.x; sq.y = o.y * o.y; sq.z = o.z * o.z; sq.w = o.w * o.w;
        ls[threadIdx.x] = o; lq[threadIdx.x] = sq;
        __syncthreads();
        if (threadIdx.x < 16) {
            float4 S = make_float4(0.f, 0.f, 0.f, 0.f);
            float4 Q = make_float4(0.f, 0.f, 0.f, 0.f);
            for (int g = 0; g < 16; g++) {
                float4 a = ls[g * 16 + threadIdx.x], c = lq[g * 16 + threadIdx.x];
                S.x += a.x; S.y += a.y; S.z += a.z; S.w += a.w;
                Q.x += c.x; Q.y += c.y; Q.z += c.z; Q.w += c.w;
            }
            float4* dst = (float4*)(pbuf + (size_t)blockIdx.x * 128);
            dst[threadIdx.x] = S;
            dst[threadIdx.x + 16] = Q;
        }
    }
}

// ---------------- gemmAB_mfma: hs2 = fp16(dis * ((ag1@W1 + b1) @ W2)) ----------------
#define SH_PAD 136
__global__ __launch_bounds__(256) void gemmAB_mfma_k(const f16* __restrict__ ag1,
                                                     const f16* __restrict__ w1t,
                                                     const float* __restrict__ b1,
                                                     const f16* __restrict__ w2t,
                                                     const float* __restrict__ dis,
                                                     f16* __restrict__ hs2, int n) {
    __shared__ f16 sH[64 * SH_PAD];               // 17.4KB
    int tid = threadIdx.x;
    int w = tid >> 6, l = tid & 63;
    int cl = l & 15, ko = (l >> 4) * 8, r0 = (l >> 4) * 4;
    int rowbase = blockIdx.x * 64;
    int mrow = rowbase + w * 16;

    f16x8 a0 = *(const f16x8*)(ag1 + (size_t)(mrow + cl) * 64 + ko);
    f16x8 a1 = *(const f16x8*)(ag1 + (size_t)(mrow + cl) * 64 + 32 + ko);
#pragma unroll
    for (int nt = 0; nt < 8; nt++) {
        f32x4 acc = {0.f, 0.f, 0.f, 0.f};
        f16x8 b0 = *(const f16x8*)(w1t + (nt * 16 + cl) * 64 + ko);
        f16x8 b1f = *(const f16x8*)(w1t + (nt * 16 + cl) * 64 + 32 + ko);
        acc = __builtin_amdgcn_mfma_f32_16x16x32_f16(a0, b0, acc, 0, 0, 0);
        acc = __builtin_amdgcn_mfma_f32_16x16x32_f16(a1, b1f, acc, 0, 0, 0);
        float bias = b1[nt * 16 + cl];
#pragma unroll
        for (int j = 0; j < 4; j++)
            sH[(w * 16 + r0 + j) * SH_PAD + nt * 16 + cl] = (f16)(acc[j] + bias);
    }
    __syncthreads();
#pragma unroll
    for (int nt = 0; nt < 4; nt++) {
        f32x4 acc = {0.f, 0.f, 0.f, 0.f};
#pragma unroll
        for (int s = 0; s < 4; s++) {
            f16x8 a = *(const f16x8*)(&sH[(w * 16 + cl) * SH_PAD + s * 32 + ko]);
            f16x8 b = *(const f16x8*)(w2t + (nt * 16 + cl) * 128 + s * 32 + ko);
            acc = __builtin_amdgcn_mfma_f32_16x16x32_f16(a, b, acc, 0, 0, 0);
        }
#pragma unroll
        for (int j = 0; j < 4; j++) {
            int row = mrow + r0 + j;
            if (row < n) {
                float d = dis[row];
                hs2[(size_t)row * 64 + nt * 16 + cl] = (f16)(acc[j] * d);
            }
        }
    }
}

// ---------------- bn_final: reduce nb per-block partials -> scale/shift ----------------
__global__ __launch_bounds__(1024) void bn_final_k(const float* __restrict__ pbuf,
                                                   const float* __restrict__ gamma,
                                                   const float* __restrict__ beta,
                                                   int n, int nb,
                                                   float* __restrict__ scale, float* __restrict__ shift) {
    __shared__ float ls[1024], lq[1024];
    int c = threadIdx.x & 63, part = threadIdx.x >> 6;    // 16 slices
    float s = 0.f, q = 0.f;
    for (int b = part; b < nb; b += 16) {
        s += pbuf[(size_t)b * 128 + c];
        q += pbuf[(size_t)b * 128 + 64 + c];
    }
    ls[threadIdx.x] = s; lq[threadIdx.x] = q;
    __syncthreads();
    if (threadIdx.x < 64) {
        s = 0.f; q = 0.f;
        for (int k = 0; k < 16; k++) {
            s += ls[k * 64 + c];
            q += lq[k * 64 + c];
        }
        float inv_n = 1.f / (float)n;
        float mean = s * inv_n;
        float var = q * inv_n - mean * mean;      // biased variance
        float sc = gamma[c] * rsqrtf(var + EPS_BN);
        scale[c] = sc;
        shift[c] = beta[c] - mean * sc;
    }
}

// ---------------- bn_apply: h2 fp16 -> d_out f32 ----------------
__global__ __launch_bounds__(256) void bn_apply_k(const f16* __restrict__ x, const float* __restrict__ scale,
                                                  const float* __restrict__ shift, float* __restrict__ out, int n) {
    __shared__ float sscale[64], sshift[64];
    if (threadIdx.x < 64) {
        sscale[threadIdx.x] = scale[threadIdx.x];
        sshift[threadIdx.x] = shift[threadIdx.x];
    }
    __syncthreads();
    int i = blockIdx.x * 256 + threadIdx.x;
    if (i < n * 16) {
        int c = (i & 15) * 4;
        pk4 p; p.u = ((const ushort4*)x)[i];
        float4 o;
        o.x = (float)p.h[0] * sscale[c]     + sshift[c];
        o.y = (float)p.h[1] * sscale[c + 1] + sshift[c + 1];
        o.z = (float)p.h[2] * sscale[c + 2] + sshift[c + 2];
        o.w = (float)p.h[3] * sscale[c + 3] + sshift[c + 3];
        ((float4*)out)[i] = o;
    }
}

extern "C" void kernel_launch(void* const* d_in, const int* in_sizes, int n_in,
                              void* d_out, int out_size, void* d_ws, size_t ws_size,
                              hipStream_t stream) {
    const float* emb   = (const float*)d_in[0];
    const float* W1    = (const float*)d_in[1];
    const float* b1    = (const float*)d_in[2];
    const float* W2    = (const float*)d_in[3];
    const float* b2    = (const float*)d_in[4];
    const float* gamma = (const float*)d_in[5];
    const float* beta  = (const float*)d_in[6];
    const int*   ei    = (const int*)d_in[7];     // [2,E] int32
    const int n = in_sizes[0] / 64;               // 100000
    const int E = in_sizes[7] / 2;                // 1600000
    const int* rowv = ei;                         // sources
    const int* colv = ei + E;                     // targets
    const int NBKT = (n + 127) / 128;             // 782
    const int NAGG = (n + 15) / 16;               // 6250 agg blocks

    char* ws = (char*)d_ws;
    size_t o = 0;
    auto alloc = [&](size_t bytes) -> char* {
        char* p = ws + o;
        o = (o + bytes + 255) & ~(size_t)255;
        return p;
    };
    int*   ghist   = (int*)alloc((size_t)SCAT_B * NBKT_PAD * 4);  // 1MB
    int*   bcnt    = (int*)alloc(NBKT_PAD * 4);
    int*   bstart  = (int*)alloc((NBKT_PAD + 1) * 4);
    int*   start   = (int*)alloc((size_t)(n + 1) * 4);
    float* dis     = (float*)alloc((size_t)n * 4);
    int*   srcs    = (int*)alloc((size_t)E * 4);
    float* pbuf    = (float*)alloc((size_t)NAGG * 128 * 4);       // BN partials (3.2MB)
    float* bnscale = (float*)alloc(256);
    float* bnshift = (float*)alloc(256);
    f16*   w1t     = (f16*)alloc(128 * 64 * 2);          // W1^T f16 [n][k]
    f16*   w2t     = (f16*)alloc(64 * 128 * 2);          // W2^T f16 [n][k]
    f16*   es      = (f16*)alloc((size_t)n * 64 * 2);    // dis*emb fp16
    f16*   ag1     = (f16*)alloc((size_t)n * 64 * 2);    // layer-1 aggregated
    f16*   hs2     = (f16*)alloc((size_t)n * 64 * 2);    // dis*((ag1@W1+b1)@W2)
    f16*   h2      = (f16*)alloc((size_t)n * 64 * 2);    // pre-BN output
    unsigned* ebuf = (unsigned*)alloc((size_t)E * 4);    // packed bucket edges

    int epb = (E + SCAT_B - 1) / SCAT_B;          // 6250

    hist_k<<<SCAT_B, 1024, 0, stream>>>(colv, E, epb, ghist, W1, W2, w1t, w2t);
    scan_bucket_k<<<NBKT_PAD, 256, 0, stream>>>(ghist, bcnt);
    scan_total_k<<<1, 1024, 0, stream>>>(bcnt, bstart, start, n, E);
    scatB_k<<<SCAT_B, 1024, 0, stream>>>(rowv, colv, E, epb, ghist, bstart, ebuf);
    buildC_k<<<NBKT, 512, 0, stream>>>(ebuf, bstart, start, srcs, dis, emb, es, n);

    agg64_k<<<NAGG, 256, 0, stream>>>(es, start, srcs, dis, nullptr, ag1, nullptr, n);
    gemmAB_mfma_k<<<(n + 63) / 64, 256, 0, stream>>>(ag1, w1t, b1, w2t, dis, hs2, n);
    agg64_k<<<NAGG, 256, 0, stream>>>(hs2, start, srcs, dis, b2, h2, pbuf, n);

    bn_final_k<<<1, 1024, 0, stream>>>(pbuf, gamma, beta, n, NAGG, bnscale, bnshift);
    bn_apply_k<<<(n * 16 + 255) / 256, 256, 0, stream>>>(h2, bnscale, bnshift, (float*)d_out, n);
}

// Round 14
// 177.292 us; speedup vs baseline: 1.5731x; 1.5731x over previous
//
#include <hip/hip_runtime.h>

// GCN 2-layer + BatchNorm1d forward.
// R14: fix R13's regression (bn_final single block reducing 3.2MB of per-agg-
//      block BN partials = 118us single-CU-bandwidth-bound; lesson: single-
//      block kernels may only touch KBs). Two-stage reduce: bn_red (128 blocks,
//      coalesced, 6250->128 rows) -> bn_final (64 thr over 64KB, R12 shape).
// Kept from R13: wprep in hist block 0; prescale in buildC; bn_part fused into
//      layer-2 agg64 (per-block partials, plain stores); counting-sort CSR;
//      R8-form agg64 gathers (FETCH = 86MB unique-line floor, ~3.4TB/s fill
//      ceiling -> ~27us each is the floor); MFMA GEMM (verified layouts).
// Pipeline: hist(+wprep) -> scan_bucket -> scan_total -> scatB ->
//   buildC(CSR+dis+es) -> agg64 ag1 -> gemmAB_mfma hs2 -> agg64 h2(+BN part)
//   -> bn_red -> bn_final -> bn_apply -> d_out f32.

#define EPS_BN 1e-5f
#define NBKT_PAD 1024   // >= ceil(N/128); N=100000 -> 782 buckets
#define SCAT_B 256      // edge-pass blocks (1024 threads each)
#define RED_B 128       // bn_red blocks (stage-1 reduction slots)

typedef _Float16 f16;
typedef _Float16 f16x2 __attribute__((ext_vector_type(2)));
typedef _Float16 f16x8 __attribute__((ext_vector_type(8)));
typedef float f32x4 __attribute__((ext_vector_type(4)));
union pk4 { ushort4 u; f16 h[4]; f16x2 h2[2]; };

// ---------------- hist (+wprep in block 0) ----------------
__global__ __launch_bounds__(1024) void hist_k(const int* __restrict__ colv, int E, int epb,
                                               int* __restrict__ ghist,
                                               const float* __restrict__ W1, const float* __restrict__ W2,
                                               f16* __restrict__ w1t, f16* __restrict__ w2t) {
    __shared__ int bins[NBKT_PAD];
    int tid = threadIdx.x;
    bins[tid] = 0;
    __syncthreads();
    int e0 = blockIdx.x * epb;
    int e1 = min(E, e0 + epb);
    for (int e = e0 + tid; e < e1; e += 1024)
        atomicAdd(&bins[colv[e] >> 7], 1);
    __syncthreads();
    ghist[blockIdx.x * NBKT_PAD + tid] = bins[tid];
    if (blockIdx.x == 0) {                        // fused wprep
        for (int t = tid; t < 16384; t += 1024) {
            if (t < 8192) {                       // W1 [64][128] -> w1t [128][64]
                int k = t >> 7, c = t & 127;
                w1t[c * 64 + k] = (f16)W1[t];
            } else {                              // W2 [128][64] -> w2t [64][128]
                int i = t - 8192;
                int k = i >> 6, c = i & 63;
                w2t[c * 128 + k] = (f16)W2[i];
            }
        }
    }
}

// ---------------- scan_bucket: per-bucket exclusive prefix over the 256 blocks ----------------
__global__ __launch_bounds__(256) void scan_bucket_k(int* __restrict__ ghist, int* __restrict__ bcnt) {
    __shared__ int s[256];
    int k = blockIdx.x;
    int b = threadIdx.x;
    int v = ghist[b * NBKT_PAD + k];
    s[b] = v; __syncthreads();
    for (int off = 1; off < 256; off <<= 1) {
        int t = (b >= off) ? s[b - off] : 0;
        __syncthreads();
        s[b] += t;
        __syncthreads();
    }
    ghist[b * NBKT_PAD + k] = s[b] - v;           // exclusive within bucket
    if (b == 255) bcnt[k] = s[255];
}

// ---------------- scan_total: exclusive scan of bucket totals ----------------
__global__ __launch_bounds__(1024) void scan_total_k(const int* __restrict__ bcnt,
                                                     int* __restrict__ bstart,
                                                     int* __restrict__ start, int n, int E) {
    __shared__ int s[1024];
    int tid = threadIdx.x;
    int v = bcnt[tid];
    s[tid] = v; __syncthreads();
    for (int off = 1; off < 1024; off <<= 1) {
        int t = (tid >= off) ? s[tid - off] : 0;
        __syncthreads();
        s[tid] += t;
        __syncthreads();
    }
    bstart[tid] = s[tid] - v;
    if (tid == 1023) bstart[1024] = s[1023];
    if (tid == 0) start[n] = E;
}

// ---------------- scatB: single-pass scatter (cursor = ghist + bstart) ----------------
__global__ __launch_bounds__(1024) void scatB_k(const int* __restrict__ rowv, const int* __restrict__ colv,
                                                int E, int epb, const int* __restrict__ ghist,
                                                const int* __restrict__ bstart,
                                                unsigned* __restrict__ ebuf) {
    __shared__ int bins[NBKT_PAD];
    int tid = threadIdx.x;
    bins[tid] = ghist[blockIdx.x * NBKT_PAD + tid] + bstart[tid];
    __syncthreads();
    int e0 = blockIdx.x * epb;
    int e1 = min(E, e0 + epb);
    for (int e = e0 + tid; e < e1; e += 1024) {
        int c = colv[e];
        int p = atomicAdd(&bins[c >> 7], 1);
        ebuf[p] = ((unsigned)rowv[e] << 7) | (unsigned)(c & 127);
    }
}

// ---------------- buildC: per-bucket CSR finalize + fused prescale (es) ----------------
__global__ __launch_bounds__(512) void buildC_k(const unsigned* __restrict__ ebuf,
                                                const int* __restrict__ bstart,
                                                int* __restrict__ start, int* __restrict__ srcs,
                                                float* __restrict__ dis,
                                                const float* __restrict__ emb, f16* __restrict__ es, int n) {
    __shared__ int ncnt[128], noff[128], stmp[128];
    __shared__ float sdis[128];
    int b = blockIdx.x;
    int tid = threadIdx.x;
    int e0 = bstart[b], e1 = bstart[b + 1];
    if (tid < 128) ncnt[tid] = 0;
    __syncthreads();
    for (int e = e0 + tid; e < e1; e += 512)
        atomicAdd(&ncnt[ebuf[e] & 127u], 1);
    __syncthreads();
    if (tid < 128) stmp[tid] = ncnt[tid];
    __syncthreads();
    for (int off = 1; off < 128; off <<= 1) {
        int t = (tid < 128 && tid >= off) ? stmp[tid - off] : 0;
        __syncthreads();
        if (tid < 128) stmp[tid] += t;
        __syncthreads();
    }
    if (tid < 128) {
        int excl = stmp[tid] - ncnt[tid];
        noff[tid] = e0 + excl;
        float d = rsqrtf((float)(ncnt[tid] + 1));         // +1 self-loop
        sdis[tid] = d;
        int node = b * 128 + tid;
        if (node < n) {
            start[node] = e0 + excl;
            dis[node] = d;
        }
    }
    __syncthreads();
    for (int e = e0 + tid; e < e1; e += 512) {
        unsigned p = ebuf[e];
        int pos = atomicAdd(&noff[p & 127u], 1);
        srcs[pos] = (int)(p >> 7);
    }
    // fused prescale: es[node] = fp16(dis * emb[node]) for this bucket's nodes
    for (int i = tid; i < 2048; i += 512) {               // 128 rows x 16 quads
        int r = i >> 4, q = i & 15;
        int node = b * 128 + r;
        if (node < n) {
            float d = sdis[r];
            float4 v = ((const float4*)emb)[(size_t)node * 16 + q];
            pk4 p;
            p.h[0] = (f16)(v.x * d); p.h[1] = (f16)(v.y * d);
            p.h[2] = (f16)(v.z * d); p.h[3] = (f16)(v.w * d);
            ((ushort4*)es)[(size_t)node * 16 + q] = p.u;
        }
    }
}

__device__ __forceinline__ void acc_pk(float4& acc, ushort4 u) {
    pk4 p; p.u = u;
    acc.x += (float)p.h[0]; acc.y += (float)p.h[1];
    acc.z += (float)p.h[2]; acc.w += (float)p.h[3];
}

// ---------------- agg64: 16 lanes/node, 8-deep unroll, pure gather ----------------
// If pbuf != null, also emits per-block BN partials (sum, sumsq per column).
__global__ __launch_bounds__(256) void agg64_k(const f16* __restrict__ table, const int* __restrict__ start,
                                               const int* __restrict__ srcs, const float* __restrict__ dis,
                                               const float* __restrict__ bias, f16* __restrict__ out,
                                               float* __restrict__ pbuf, int n) {
    __shared__ float4 ls[256], lq[256];
    int node = blockIdx.x * 16 + (threadIdx.x >> 4);
    bool active = node < n;
    int lane = threadIdx.x & 15;
    const ushort4* t4 = (const ushort4*)table;
    float4 acc = make_float4(0.f, 0.f, 0.f, 0.f);
    int s0 = 0, s1 = 0;
    if (active) {
        acc_pk(acc, t4[(size_t)node * 16 + lane]);        // self-loop term
        s0 = start[node]; s1 = start[node + 1];
    }
    int e = s0;
    for (; e + 7 < s1; e += 8) {
        int i0 = srcs[e],     i1 = srcs[e + 1], i2 = srcs[e + 2], i3 = srcs[e + 3];
        int i4 = srcs[e + 4], i5 = srcs[e + 5], i6 = srcs[e + 6], i7 = srcs[e + 7];
        ushort4 v0 = t4[(size_t)i0 * 16 + lane];
        ushort4 v1 = t4[(size_t)i1 * 16 + lane];
        ushort4 v2 = t4[(size_t)i2 * 16 + lane];
        ushort4 v3 = t4[(size_t)i3 * 16 + lane];
        ushort4 v4 = t4[(size_t)i4 * 16 + lane];
        ushort4 v5 = t4[(size_t)i5 * 16 + lane];
        ushort4 v6 = t4[(size_t)i6 * 16 + lane];
        ushort4 v7 = t4[(size_t)i7 * 16 + lane];
        acc_pk(acc, v0); acc_pk(acc, v1); acc_pk(acc, v2); acc_pk(acc, v3);
        acc_pk(acc, v4); acc_pk(acc, v5); acc_pk(acc, v6); acc_pk(acc, v7);
    }
    for (; e + 3 < s1; e += 4) {
        int i0 = srcs[e], i1 = srcs[e + 1], i2 = srcs[e + 2], i3 = srcs[e + 3];
        ushort4 v0 = t4[(size_t)i0 * 16 + lane];
        ushort4 v1 = t4[(size_t)i1 * 16 + lane];
        ushort4 v2 = t4[(size_t)i2 * 16 + lane];
        ushort4 v3 = t4[(size_t)i3 * 16 + lane];
        acc_pk(acc, v0); acc_pk(acc, v1); acc_pk(acc, v2); acc_pk(acc, v3);
    }
    for (; e < s1; e++) acc_pk(acc, t4[(size_t)srcs[e] * 16 + lane]);
    float4 o = make_float4(0.f, 0.f, 0.f, 0.f);
    if (active) {
        float d = dis[node];
        float4 b = make_float4(0.f, 0.f, 0.f, 0.f);
        if (bias) b = ((const float4*)bias)[lane];
        o.x = acc.x * d + b.x; o.y = acc.y * d + b.y;
        o.z = acc.z * d + b.z; o.w = acc.w * d + b.w;
        pk4 p;
        p.h[0] = (f16)o.x; p.h[1] = (f16)o.y; p.h[2] = (f16)o.z; p.h[3] = (f16)o.w;
        ((ushort4*)out)[(size_t)node * 16 + lane] = p.u;
    }
    if (pbuf) {                                   // fused BN partials (uniform branch)
        float4 sq;
        sq.x = o.x * o.x; sq.y = o.y * o.y; sq.z = o.z * o.z; sq.w = o.w * o.w;
        ls[threadIdx.x] = o; lq[threadIdx.x] = sq;
        __syncthreads();
        if (threadIdx.x < 16) {
            float4 S = make_float4(0.f, 0.f, 0.f, 0.f);
            float4 Q = make_float4(0.f, 0.f, 0.f, 0.f);
            for (int g = 0; g < 16; g++) {
                float4 a = ls[g * 16 + threadIdx.x], c = lq[g * 16 + threadIdx.x];
                S.x += a.x; S.y += a.y; S.z += a.z; S.w += a.w;
                Q.x += c.x; Q.y += c.y; Q.z += c.z; Q.w += c.w;
            }
            float4* dst = (float4*)(pbuf + (size_t)blockIdx.x * 128);
            dst[threadIdx.x] = S;
            dst[threadIdx.x + 16] = Q;
        }
    }
}

// ---------------- gemmAB_mfma: hs2 = fp16(dis * ((ag1@W1 + b1) @ W2)) ----------------
#define SH_PAD 136
__global__ __launch_bounds__(256) void gemmAB_mfma_k(const f16* __restrict__ ag1,
                                                     const f16* __restrict__ w1t,
                                                     const float* __restrict__ b1,
                                                     const f16* __restrict__ w2t,
                                                     const float* __restrict__ dis,
                                                     f16* __restrict__ hs2, int n) {
    __shared__ f16 sH[64 * SH_PAD];               // 17.4KB
    int tid = threadIdx.x;
    int w = tid >> 6, l = tid & 63;
    int cl = l & 15, ko = (l >> 4) * 8, r0 = (l >> 4) * 4;
    int rowbase = blockIdx.x * 64;
    int mrow = rowbase + w * 16;

    f16x8 a0 = *(const f16x8*)(ag1 + (size_t)(mrow + cl) * 64 + ko);
    f16x8 a1 = *(const f16x8*)(ag1 + (size_t)(mrow + cl) * 64 + 32 + ko);
#pragma unroll
    for (int nt = 0; nt < 8; nt++) {
        f32x4 acc = {0.f, 0.f, 0.f, 0.f};
        f16x8 b0 = *(const f16x8*)(w1t + (nt * 16 + cl) * 64 + ko);
        f16x8 b1f = *(const f16x8*)(w1t + (nt * 16 + cl) * 64 + 32 + ko);
        acc = __builtin_amdgcn_mfma_f32_16x16x32_f16(a0, b0, acc, 0, 0, 0);
        acc = __builtin_amdgcn_mfma_f32_16x16x32_f16(a1, b1f, acc, 0, 0, 0);
        float bias = b1[nt * 16 + cl];
#pragma unroll
        for (int j = 0; j < 4; j++)
            sH[(w * 16 + r0 + j) * SH_PAD + nt * 16 + cl] = (f16)(acc[j] + bias);
    }
    __syncthreads();
#pragma unroll
    for (int nt = 0; nt < 4; nt++) {
        f32x4 acc = {0.f, 0.f, 0.f, 0.f};
#pragma unroll
        for (int s = 0; s < 4; s++) {
            f16x8 a = *(const f16x8*)(&sH[(w * 16 + cl) * SH_PAD + s * 32 + ko]);
            f16x8 b = *(const f16x8*)(w2t + (nt * 16 + cl) * 128 + s * 32 + ko);
            acc = __builtin_amdgcn_mfma_f32_16x16x32_f16(a, b, acc, 0, 0, 0);
        }
#pragma unroll
        for (int j = 0; j < 4; j++) {
            int row = mrow + r0 + j;
            if (row < n) {
                float d = dis[row];
                hs2[(size_t)row * 64 + nt * 16 + cl] = (f16)(acc[j] * d);
            }
        }
    }
}

// ---------------- bn_red: stage-1 reduce, nb partial rows -> RED_B rows ----------------
__global__ __launch_bounds__(256) void bn_red_k(const float* __restrict__ pbuf, int nb,
                                                float* __restrict__ rbuf) {
    __shared__ float ls[256];
    int c = threadIdx.x & 127;    // column 0..127 (sum | sumsq)
    int half = threadIdx.x >> 7;  // 0..1
    int per = (nb + RED_B - 1) / RED_B;
    int r0 = blockIdx.x * per;
    int r1 = min(nb, r0 + per);
    float s = 0.f;
    for (int r = r0 + half; r < r1; r += 2)       // coalesced 512B row reads
        s += pbuf[(size_t)r * 128 + c];
    ls[threadIdx.x] = s;
    __syncthreads();
    if (threadIdx.x < 128)
        rbuf[blockIdx.x * 128 + threadIdx.x] = ls[threadIdx.x] + ls[threadIdx.x + 128];
}

// ---------------- bn_final: reduce RED_B rows (64KB) -> scale/shift ----------------
__global__ __launch_bounds__(64) void bn_final_k(const float* __restrict__ rbuf,
                                                 const float* __restrict__ gamma,
                                                 const float* __restrict__ beta,
                                                 int n, float* __restrict__ scale, float* __restrict__ shift) {
    int c = threadIdx.x;
    float s = 0.f, q = 0.f;
    for (int b = 0; b < RED_B; b++) {
        s += rbuf[b * 128 + c];
        q += rbuf[b * 128 + 64 + c];
    }
    float inv_n = 1.f / (float)n;
    float mean = s * inv_n;
    float var = q * inv_n - mean * mean;          // biased variance
    float sc = gamma[c] * rsqrtf(var + EPS_BN);
    scale[c] = sc;
    shift[c] = beta[c] - mean * sc;
}

// ---------------- bn_apply: h2 fp16 -> d_out f32 ----------------
__global__ __launch_bounds__(256) void bn_apply_k(const f16* __restrict__ x, const float* __restrict__ scale,
                                                  const float* __restrict__ shift, float* __restrict__ out, int n) {
    __shared__ float sscale[64], sshift[64];
    if (threadIdx.x < 64) {
        sscale[threadIdx.x] = scale[threadIdx.x];
        sshift[threadIdx.x] = shift[threadIdx.x];
    }
    __syncthreads();
    int i = blockIdx.x * 256 + threadIdx.x;
    if (i < n * 16) {
        int c = (i & 15) * 4;
        pk4 p; p.u = ((const ushort4*)x)[i];
        float4 o;
        o.x = (float)p.h[0] * sscale[c]     + sshift[c];
        o.y = (float)p.h[1] * sscale[c + 1] + sshift[c + 1];
        o.z = (float)p.h[2] * sscale[c + 2] + sshift[c + 2];
        o.w = (float)p.h[3] * sscale[c + 3] + sshift[c + 3];
        ((float4*)out)[i] = o;
    }
}

extern "C" void kernel_launch(void* const* d_in, const int* in_sizes, int n_in,
                              void* d_out, int out_size, void* d_ws, size_t ws_size,
                              hipStream_t stream) {
    const float* emb   = (const float*)d_in[0];
    const float* W1    = (const float*)d_in[1];
    const float* b1    = (const float*)d_in[2];
    const float* W2    = (const float*)d_in[3];
    const float* b2    = (const float*)d_in[4];
    const float* gamma = (const float*)d_in[5];
    const float* beta  = (const float*)d_in[6];
    const int*   ei    = (const int*)d_in[7];     // [2,E] int32
    const int n = in_sizes[0] / 64;               // 100000
    const int E = in_sizes[7] / 2;                // 1600000
    const int* rowv = ei;                         // sources
    const int* colv = ei + E;                     // targets
    const int NBKT = (n + 127) / 128;             // 782
    const int NAGG = (n + 15) / 16;               // 6250 agg blocks

    char* ws = (char*)d_ws;
    size_t o = 0;
    auto alloc = [&](size_t bytes) -> char* {
        char* p = ws + o;
        o = (o + bytes + 255) & ~(size_t)255;
        return p;
    };
    int*   ghist   = (int*)alloc((size_t)SCAT_B * NBKT_PAD * 4);  // 1MB
    int*   bcnt    = (int*)alloc(NBKT_PAD * 4);
    int*   bstart  = (int*)alloc((NBKT_PAD + 1) * 4);
    int*   start   = (int*)alloc((size_t)(n + 1) * 4);
    float* dis     = (float*)alloc((size_t)n * 4);
    int*   srcs    = (int*)alloc((size_t)E * 4);
    float* pbuf    = (float*)alloc((size_t)NAGG * 128 * 4);       // BN partials (3.2MB)
    float* rbuf    = (float*)alloc((size_t)RED_B * 128 * 4);      // stage-1 reduced (64KB)
    float* bnscale = (float*)alloc(256);
    float* bnshift = (float*)alloc(256);
    f16*   w1t     = (f16*)alloc(128 * 64 * 2);          // W1^T f16 [n][k]
    f16*   w2t     = (f16*)alloc(64 * 128 * 2);          // W2^T f16 [n][k]
    f16*   es      = (f16*)alloc((size_t)n * 64 * 2);    // dis*emb fp16
    f16*   ag1     = (f16*)alloc((size_t)n * 64 * 2);    // layer-1 aggregated
    f16*   hs2     = (f16*)alloc((size_t)n * 64 * 2);    // dis*((ag1@W1+b1)@W2)
    f16*   h2      = (f16*)alloc((size_t)n * 64 * 2);    // pre-BN output
    unsigned* ebuf = (unsigned*)alloc((size_t)E * 4);    // packed bucket edges

    int epb = (E + SCAT_B - 1) / SCAT_B;          // 6250

    hist_k<<<SCAT_B, 1024, 0, stream>>>(colv, E, epb, ghist, W1, W2, w1t, w2t);
    scan_bucket_k<<<NBKT_PAD, 256, 0, stream>>>(ghist, bcnt);
    scan_total_k<<<1, 1024, 0, stream>>>(bcnt, bstart, start, n, E);
    scatB_k<<<SCAT_B, 1024, 0, stream>>>(rowv, colv, E, epb, ghist, bstart, ebuf);
    buildC_k<<<NBKT, 512, 0, stream>>>(ebuf, bstart, start, srcs, dis, emb, es, n);

    agg64_k<<<NAGG, 256, 0, stream>>>(es, start, srcs, dis, nullptr, ag1, nullptr, n);
    gemmAB_mfma_k<<<(n + 63) / 64, 256, 0, stream>>>(ag1, w1t, b1, w2t, dis, hs2, n);
    agg64_k<<<NAGG, 256, 0, stream>>>(hs2, start, srcs, dis, b2, h2, pbuf, n);

    bn_red_k<<<RED_B, 256, 0, stream>>>(pbuf, NAGG, rbuf);
    bn_final_k<<<1, 64, 0, stream>>>(rbuf, gamma, beta, n, bnscale, bnshift);
    bn_apply_k<<<(n * 16 + 255) / 256, 256, 0, stream>>>(h2, bnscale, bnshift, (float*)d_out, n);
}